// Round 3
// baseline (320.629 us; speedup 1.0000x reference)
//
#include <hip/hip_runtime.h>

#define S_DIM 1024
#define TQ 16
#define LOG2E 1.44269504f

typedef __attribute__((ext_vector_type(4))) float f32x4;
typedef __attribute__((ext_vector_type(4))) int i32x4;
typedef _Float16 half4 __attribute__((ext_vector_type(4)));
typedef _Float16 half8 __attribute__((ext_vector_type(8)));

__device__ inline half8 pack8h(f32x4 a, f32x4 b) {
  half8 r;
  r[0] = (_Float16)a.x; r[1] = (_Float16)a.y;
  r[2] = (_Float16)a.z; r[3] = (_Float16)a.w;
  r[4] = (_Float16)b.x; r[5] = (_Float16)b.y;
  r[6] = (_Float16)b.z; r[7] = (_Float16)b.w;
  return r;
}

// ---------- prep: K -> f16 (same layout), V -> f16 transposed [bh][d][k] ----------
__global__ __launch_bounds__(256)
void prep_kernel(const float* __restrict__ kp, const float* __restrict__ vp,
                 _Float16* __restrict__ k16, _Float16* __restrict__ vt16)
{
  __shared__ _Float16 tile[64][72];
  const int tid = threadIdx.x;
  const int bh  = blockIdx.x >> 4;             // 32 (b,h) pairs
  const int c0  = (blockIdx.x & 15) * 64;      // 64-row k-chunk
  const size_t base = ((size_t)bh * S_DIM + c0) * 64;

  #pragma unroll
  for (int i = 0; i < 4; ++i) {
    const int idx = i * 256 + tid;
    f32x4 kv = *(const f32x4*)(kp + base + (size_t)idx * 4);
    half4 h; h[0] = (_Float16)kv.x; h[1] = (_Float16)kv.y;
    h[2] = (_Float16)kv.z; h[3] = (_Float16)kv.w;
    *(half4*)(k16 + base + (size_t)idx * 4) = h;
  }
  #pragma unroll
  for (int i = 0; i < 4; ++i) {
    const int idx = i * 256 + tid;
    const int r = idx >> 4, c4 = idx & 15;
    f32x4 vv = *(const f32x4*)(vp + base + (size_t)r * 64 + c4 * 4);
    tile[c4 * 4 + 0][r] = (_Float16)vv.x;
    tile[c4 * 4 + 1][r] = (_Float16)vv.y;
    tile[c4 * 4 + 2][r] = (_Float16)vv.z;
    tile[c4 * 4 + 3][r] = (_Float16)vv.w;
  }
  __syncthreads();
  #pragma unroll
  for (int i = 0; i < 2; ++i) {
    const int idx = i * 256 + tid;
    const int d = idx >> 3, g = idx & 7;
    half8 h = *(half8*)&tile[d][g * 8];
    *(half8*)(vt16 + ((size_t)bh * 64 + d) * S_DIM + c0 + g * 8) = h;
  }
}

// ---------- maskpack: mask[b][row][k] i32 -> pm[b*S+row][32] bit-dwords ----------
__global__ __launch_bounds__(256)
void maskpack_kernel(const int* __restrict__ maskp, unsigned int* __restrict__ pm)
{
  const int tid  = threadIdx.x;
  const int lane = tid & 63;
  const int wave = tid >> 6;
  const int row  = blockIdx.x;                 // 4096 rows (b*1024 + r)
  const size_t base = (size_t)row * S_DIM + wave * 256;
  unsigned long long bal0, bal1, bal2, bal3;
  bal0 = __ballot(maskp[base +   0 + lane] != 0);
  bal1 = __ballot(maskp[base +  64 + lane] != 0);
  bal2 = __ballot(maskp[base + 128 + lane] != 0);
  bal3 = __ballot(maskp[base + 192 + lane] != 0);
  if (lane == 0) {
    unsigned long long* dst =
        (unsigned long long*)(pm + (size_t)row * 32 + wave * 8);
    dst[0] = bal0; dst[1] = bal1; dst[2] = bal2; dst[3] = bal3;
  }
}

// ---------- main: one barrier, 4 blocks/CU, surviving sph pipeline ----------
__global__ __launch_bounds__(256, 4)
void sdpa_kernel(const float* __restrict__ qp,
                 const _Float16* __restrict__ k16,
                 const _Float16* __restrict__ vt16,
                 const float* __restrict__ sphp,
                 const unsigned int* __restrict__ pm,
                 float* __restrict__ outp, float* __restrict__ pp)
{
  __shared__ _Float16 pb[TQ][1032];   // scores*log2e -> e (f16)
  __shared__ float    red[4][16];     // per-wave row sums

  const int tid   = threadIdx.x;
  const int lane  = tid & 63;
  const int wave  = tid >> 6;
  const int row16 = lane & 15;        // MFMA m/n index
  const int quad  = lane >> 4;        // MFMA k-chunk / C row-quad

  const int bh = blockIdx.x >> 6;     // 32 (b,h) pairs
  const int qt = blockIdx.x & 63;     // 64 q-tiles of 16 rows
  const int b  = bh >> 3;             // H=8
  const int q0 = qt * TQ;
  const size_t bhS = (size_t)bh * S_DIM;

  const int kb = wave * 256;          // wave-private 256-k span
  const int ll = lane & 31;           // phase-2: lane-in-half
  const int lh = lane >> 5;           // phase-2: row parity
  const int kcol2 = kb + ll * 8;      // phase-2: 8 k per lane

  // ---- mask bits for all 16 rows: 8 dwords, loaded once (pm is L2-resident) ----
  const unsigned int* pmbase = pm + ((size_t)b * S_DIM + q0) * 32 + wave * 8 + (ll >> 2);
  unsigned int mb[8];
  #pragma unroll
  for (int i = 0; i < 8; ++i) mb[i] = pmbase[(size_t)(2 * i + lh) * 32];
  const int msh = (ll & 3) * 8;       // byte of 8 mask bits within dword

  // ---- sph bank A (rows 0..7): latency hides under all of phase 1 ----
  f32x4 sA[4][2], sB[4][2];
  #pragma unroll
  for (int i = 0; i < 4; ++i) {
    const float* p = sphp + (bhS + q0 + 2 * i + lh) * S_DIM + kcol2;
    sA[i][0] = __builtin_nontemporal_load((const f32x4*)p);
    sA[i][1] = __builtin_nontemporal_load((const f32x4*)(p + 4));
  }

  // ---------- Phase 1: S^T = K (Q/8)^T via MFMA; scores*log2e -> pb (f16) -------
  const float* qrow = qp + (bhS + q0 + row16) * 64 + quad * 8;
  const f32x4 s8 = {0.125f, 0.125f, 0.125f, 0.125f};  // 1/TEMPERATURE
  f32x4 qa = *(const f32x4*)(qrow);
  f32x4 qb = *(const f32x4*)(qrow + 4);
  f32x4 qc = *(const f32x4*)(qrow + 32);
  f32x4 qd = *(const f32x4*)(qrow + 36);
  const half8 bq0 = pack8h(qa * s8, qb * s8);
  const half8 bq1 = pack8h(qc * s8, qd * s8);

  const _Float16* kbp = k16 + (bhS + kb) * 64;
  #pragma unroll
  for (int t = 0; t < 16; ++t) {
    const _Float16* krow = kbp + (t * 16 + row16) * 64 + quad * 8;
    half8 a0 = *(const half8*)(krow);
    half8 a1 = *(const half8*)(krow + 32);
    f32x4 acc = {0.f, 0.f, 0.f, 0.f};
    acc = __builtin_amdgcn_mfma_f32_16x16x32_f16(a0, bq0, acc, 0, 0, 0);
    acc = __builtin_amdgcn_mfma_f32_16x16x32_f16(a1, bq1, acc, 0, 0, 0);
    half4 hv;
    hv[0] = (_Float16)(acc.x * LOG2E); hv[1] = (_Float16)(acc.y * LOG2E);
    hv[2] = (_Float16)(acc.z * LOG2E); hv[3] = (_Float16)(acc.w * LOG2E);
    *(half4*)&pb[row16][kb + t * 16 + quad * 4] = hv;
  }
  // NO barrier: phase 2 reads only this wave's own k-span of pb.

  // ---------- Phase 2: e = maskbit ? exp2(s2*sph) : 0 ; per-row sums ----------
  // 2 rows/iter (lane halves), 8 k/lane: b128 LDS ops (bank-balanced),
  // 5-level 32-lane reduce. No max-subtraction (|s2|<~9, e<=~420 fits f16).
  auto proc = [&](int i, const f32x4* sv, unsigned int mbi) {
    const int r = 2 * i + lh;
    half8 sh = *(half8*)&pb[r][kcol2];
    const unsigned int m = (mbi >> msh) & 0xFFu;
    float x0 = (float)sh[0] * sv[0].x, x1 = (float)sh[1] * sv[0].y;
    float x2 = (float)sh[2] * sv[0].z, x3 = (float)sh[3] * sv[0].w;
    float x4 = (float)sh[4] * sv[1].x, x5 = (float)sh[5] * sv[1].y;
    float x6 = (float)sh[6] * sv[1].z, x7 = (float)sh[7] * sv[1].w;
    float e0 = (m &   1u) ? __builtin_amdgcn_exp2f(x0) : 0.f;
    float e1 = (m &   2u) ? __builtin_amdgcn_exp2f(x1) : 0.f;
    float e2 = (m &   4u) ? __builtin_amdgcn_exp2f(x2) : 0.f;
    float e3 = (m &   8u) ? __builtin_amdgcn_exp2f(x3) : 0.f;
    float e4 = (m &  16u) ? __builtin_amdgcn_exp2f(x4) : 0.f;
    float e5 = (m &  32u) ? __builtin_amdgcn_exp2f(x5) : 0.f;
    float e6 = (m &  64u) ? __builtin_amdgcn_exp2f(x6) : 0.f;
    float e7 = (m & 128u) ? __builtin_amdgcn_exp2f(x7) : 0.f;
    half8 hv;
    hv[0] = (_Float16)e0; hv[1] = (_Float16)e1;
    hv[2] = (_Float16)e2; hv[3] = (_Float16)e3;
    hv[4] = (_Float16)e4; hv[5] = (_Float16)e5;
    hv[6] = (_Float16)e6; hv[7] = (_Float16)e7;
    *(half8*)&pb[r][kcol2] = hv;
    float sum = ((e0 + e1) + (e2 + e3)) + ((e4 + e5) + (e6 + e7));
    #pragma unroll
    for (int off = 16; off > 0; off >>= 1)
      sum += __shfl_xor(sum, off);
    if (ll == 0) red[wave][r] = sum;
  };

  #pragma unroll
  for (int i = 0; i < 4; ++i) {       // bank B (rows 8..15) in flight over proc A
    const float* p = sphp + (bhS + q0 + 8 + 2 * i + lh) * S_DIM + kcol2;
    sB[i][0] = __builtin_nontemporal_load((const f32x4*)p);
    sB[i][1] = __builtin_nontemporal_load((const f32x4*)(p + 4));
  }
  #pragma unroll
  for (int i = 0; i < 4; ++i) proc(i, sA[i], mb[i]);
  #pragma unroll
  for (int i = 0; i < 4; ++i) proc(4 + i, sB[i], mb[4 + i]);

  __syncthreads();   // the ONLY barrier: pb (all k-spans) + red now final

  // ---------- Phase 2d: p = e/sum -> nontemporal fp32 stores ----------
  #pragma unroll
  for (int i = 0; i < 8; ++i) {
    const int r = 2 * i + lh;
    const float inv = __builtin_amdgcn_rcpf(
        (red[0][r] + red[1][r]) + (red[2][r] + red[3][r]));
    half8 e = *(half8*)&pb[r][kcol2];
    f32x4 p0, p1;
    p0.x = (float)e[0] * inv; p0.y = (float)e[1] * inv;
    p0.z = (float)e[2] * inv; p0.w = (float)e[3] * inv;
    p1.x = (float)e[4] * inv; p1.y = (float)e[5] * inv;
    p1.z = (float)e[6] * inv; p1.w = (float)e[7] * inv;
    float* dst = pp + (bhS + q0 + r) * S_DIM + kcol2;
    __builtin_nontemporal_store(p0, (f32x4*)dst);
    __builtin_nontemporal_store(p1, (f32x4*)(dst + 4));
  }

  // ---------- Phase 3: O^T = V^T E^T; A-operand straight from L2-resident V^T ----
  f32x4 oacc = {0.f, 0.f, 0.f, 0.f};
  const _Float16* vrow = vt16 + ((size_t)bh * 64 + wave * 16 + row16) * S_DIM + quad * 8;
  #pragma unroll 8
  for (int c = 0; c < 32; ++c) {
    half8 af = *(const half8*)(vrow + c * 32);
    half8 bf = *(const half8*)&pb[row16][c * 32 + quad * 8];
    oacc = __builtin_amdgcn_mfma_f32_16x16x32_f16(af, bf, oacc, 0, 0, 0);
  }

  const float ssum = (red[0][row16] + red[1][row16]) + (red[2][row16] + red[3][row16]);
  const float invq = __builtin_amdgcn_rcpf(ssum);
  float* orow = outp + (bhS + q0 + row16) * 64 + wave * 16 + quad * 4;
  *(f32x4*)orow = oacc * invq;
}

extern "C" void kernel_launch(void* const* d_in, const int* in_sizes, int n_in,
                              void* d_out, int out_size, void* d_ws, size_t ws_size,
                              hipStream_t stream) {
  const float* q    = (const float*)d_in[0];
  const float* k    = (const float*)d_in[1];
  const float* v    = (const float*)d_in[2];
  const float* sph  = (const float*)d_in[3];
  const int*   mask = (const int*)d_in[4];
  float* out  = (float*)d_out;                          // [4,8,1024,64]
  float* patt = out + (size_t)4 * 8 * 1024 * 64;        // [4,8,1024,1024]

  _Float16* k16  = (_Float16*)d_ws;                     // 4 MiB
  _Float16* vt16 = k16 + (size_t)32 * S_DIM * 64;       // 4 MiB
  unsigned int* pm = (unsigned int*)(vt16 + (size_t)32 * S_DIM * 64);  // 512 KiB

  hipLaunchKernelGGL(maskpack_kernel, dim3(4 * S_DIM), dim3(256), 0, stream,
                     mask, pm);
  hipLaunchKernelGGL(prep_kernel, dim3(32 * 16), dim3(256), 0, stream,
                     k, v, k16, vt16);
  hipLaunchKernelGGL(sdpa_kernel, dim3(32 * 64), dim3(256), 0, stream,
                     q, k16, vt16, sph, pm, out, patt);
}